// Round 17
// baseline (115.445 us; speedup 1.0000x reference)
//
#include <hip/hip_runtime.h>
#include <math.h>

#define NPTS 262144
#define GBLK (NPTS / 128)     // 2048 gate blocks / 128-pt groups
#define TAU  0.01f            // refine margin threshold (logit units)

typedef float f4v __attribute__((ext_vector_type(4)));
typedef short s8v __attribute__((ext_vector_type(8)));

// manual RNE (prep only; identical rounding to HW cvt)
static __device__ __forceinline__ unsigned short f2bf(float f) {
    unsigned u = __float_as_uint(f);
    u += 0x7fffu + ((u >> 16) & 1u);
    return (unsigned short)(u >> 16);
}
// HW bf16 convert (clang lowers paired fptrunc to v_cvt_pk_bf16_f32, RNE)
static __device__ __forceinline__ unsigned short f2bf_hw(float f) {
    __bf16 b = (__bf16)f;
    unsigned short u;
    __builtin_memcpy(&u, &b, 2);
    return u;
}
static __device__ __forceinline__ float bf2f(unsigned short h) {
    return __uint_as_float(((unsigned)h) << 16);
}
static __device__ __forceinline__ unsigned pk2b(unsigned short lo, unsigned short hi) {
    return ((unsigned)hi << 16) | (unsigned)lo;
}
static __device__ __forceinline__ unsigned cpack(float lo, float hi) {
    return pk2b(f2bf_hw(lo), f2bf_hw(hi));
}
static __device__ __forceinline__ float sinrev(float x) {   // sin(2*pi*x)
    return __builtin_amdgcn_sinf(x);
}

union BFrag { uint4 q; unsigned u[4]; s8v s; };

// ---- prep: expert A-frags + biases + gw2 packs + folded gate M1/b1' + folded expert M0e/b0e' ----
__global__ __launch_bounds__(256) void prep_kernel(
    const float* __restrict__ we0, const float* __restrict__ be0,
    const float* __restrict__ wm, const float* __restrict__ bm,
    const float* __restrict__ gw1, const float* __restrict__ gw2,
    const float* __restrict__ fw, const float* __restrict__ fb,
    const float* __restrict__ gb1,
    uint4* __restrict__ packA, float* __restrict__ biasS,
    uint4* __restrict__ packGW2H, uint4* __restrict__ packGW2L,
    float* __restrict__ M1, float* __restrict__ b1p,
    float* __restrict__ M0, float* __restrict__ b0p,
    int* __restrict__ refcnt, int* __restrict__ rs_done)
{
    const int idx = blockIdx.x * 256 + threadIdx.x;
    const float PI2I = 0.15915494309189535f;
    if (idx < 12288) {
        const int l = idx & 63;
        const int fr = (idx >> 6) & 7;
        const int grp = idx >> 9;            // e*3 + ell
        const int e = grp / 3, ell = grp % 3;
        const int tau = fr >> 1, ks = fr & 1;
        const int g = l >> 4, m = l & 15;
        const int row = tau * 16 + m;
        const float scale = (ell == 0) ? (22.5f + 45.0f * (float)e) * PI2I : 30.0f * PI2I;
        const float* W = (ell == 0) ? (we0 + e * 4096) : (wm + ((ell - 1) * 8 + e) * 4096);
        unsigned short v[8];
#pragma unroll
        for (int i = 0; i < 8; i++) {
            const int k = 32 * ks + 4 * g + (i < 4 ? i : i + 12);
            v[i] = f2bf(W[row * 64 + k] * scale);
        }
        uint4 q;
        q.x = pk2b(v[0], v[1]); q.y = pk2b(v[2], v[3]);
        q.z = pk2b(v[4], v[5]); q.w = pk2b(v[6], v[7]);
        packA[idx] = q;
    } else if (idx < 13824) {
        const int j = idx - 12288;           // e*192 + ell*64 + r
        const int r = j & 63;
        const int grp = j >> 6;
        const int e = grp / 3, ell = grp % 3;
        const float scale = (ell == 0) ? (22.5f + 45.0f * (float)e) * PI2I : 30.0f * PI2I;
        const float b = (ell == 0) ? be0[e * 64 + r] : bm[((ell - 1) * 8 + e) * 64 + r];
        biasS[j] = b * scale;
    } else if (idx < 13952) {
        // gate gw2 hi/lo A-frags: rows 0..7 = gw2, rows 8..15 = 0; 2 frags (ks) x 64 lanes
        const int j = idx - 13824;           // 0..127
        const int l = j & 63;
        const int ks = j >> 6;
        const int g = l >> 4;
        const int row = l & 15;
        unsigned short vh[8], vl[8];
#pragma unroll
        for (int i = 0; i < 8; i++) {
            const int k = 32 * ks + 4 * g + (i < 4 ? i : i + 12);
            const float x = (row < 8) ? gw2[row * 64 + k] : 0.f;
            const unsigned short h = f2bf(x);
            vh[i] = h;
            vl[i] = f2bf(x - bf2f(h));
        }
        uint4 qh, ql;
        qh.x = pk2b(vh[0], vh[1]); qh.y = pk2b(vh[2], vh[3]);
        qh.z = pk2b(vh[4], vh[5]); qh.w = pk2b(vh[6], vh[7]);
        ql.x = pk2b(vl[0], vl[1]); ql.y = pk2b(vl[2], vl[3]);
        ql.z = pk2b(vl[4], vl[5]); ql.w = pk2b(vl[6], vl[7]);
        packGW2H[j] = qh; packGW2L[j] = ql;
    } else if (idx < 14144) {
        // M1 = gw1 @ fw  (64x3), fp64 accumulate
        const int m = idx - 13952;           // 0..191
        const int r = m / 3, d = m % 3;
        double s = 0.0;
        for (int j = 0; j < 64; j++) s += (double)gw1[r * 64 + j] * (double)fw[j * 3 + d];
        M1[m] = (float)s;
    } else if (idx < 14208) {
        // b1' = gw1 @ fb + gb1
        const int r = idx - 14144;           // 0..63
        double s = (double)gb1[r];
        for (int j = 0; j < 64; j++) s += (double)gw1[r * 64 + j] * (double)fb[j];
        b1p[r] = (float)s;
    } else if (idx < 15744) {
        // M0e = scale_e * (we0[e] @ fw)  (8 x 64 x 3), fp64 accumulate
        const int m = idx - 14208;           // 0..1535
        const int e = m / 192;
        const int rem = m % 192;
        const int r = rem / 3, d = rem % 3;
        const double scale = (22.5 + 45.0 * (double)e) * 0.15915494309189535;
        double s = 0.0;
        for (int j = 0; j < 64; j++) s += (double)we0[e * 4096 + r * 64 + j] * (double)fw[j * 3 + d];
        M0[m] = (float)(s * scale);
    } else if (idx < 16256) {
        // b0e' = scale_e * (we0[e] @ fb + be0[e])  (8 x 64)
        const int m = idx - 15744;           // 0..511
        const int e = m >> 6, r = m & 63;
        const double scale = (22.5 + 45.0 * (double)e) * 0.15915494309189535;
        double s = (double)be0[e * 64 + r];
        for (int j = 0; j < 64; j++) s += (double)we0[e * 4096 + r * 64 + j] * (double)fb[j];
        b0p[m] = (float)(s * scale);
    } else if (idx == 16256) {
        *refcnt = 0;
    } else if (idx == 16257) {
        *rs_done = 0;
    }
}

// ---------------- K1: gate — folded stage-1 (3 FMA/row) + MFMA stage-2 (hi/lo); zeroes out[] ----------------
// 256 threads = 4 waves x 32 points = 128 points per block.
__global__ __launch_bounds__(256) void gate_kernel(
    const float* __restrict__ coords,
    const float* __restrict__ M1, const float* __restrict__ b1p,
    const float* __restrict__ lng, const float* __restrict__ lnb,
    const float* __restrict__ gb2,
    const uint4* __restrict__ packGW2H, const uint4* __restrict__ packGW2L,
    unsigned char* __restrict__ sel, int* __restrict__ blkcnt,
    int* __restrict__ reflist, int* __restrict__ refcnt, float* __restrict__ out)
{
    __shared__ float s_M1[192], s_b1p[64], s_lng[64], s_lnb[64], s_gb2[8];
    __shared__ uint4 sW2H[128], sW2L[128];      // 4 KB
    __shared__ int s_cnt[8];
    const int t = threadIdx.x;
    if (t < 128) { sW2H[t] = packGW2H[t]; sW2L[t] = packGW2L[t]; }
    if (t < 192) s_M1[t] = M1[t];
    if (t < 64) { s_b1p[t] = b1p[t]; s_lng[t] = lng[t]; s_lnb[t] = lnb[t]; }
    if (t < 8) { s_gb2[t] = gb2[t]; s_cnt[t] = 0; }
    if (t < 128) out[blockIdx.x * 128 + t] = 0.f;
    __syncthreads();

    const int lane = t & 63;
    const int wv = t >> 6;
    const int g = lane >> 4, c = lane & 15;
    const int n0 = blockIdx.x * 128 + wv * 32 + c;
    const int n1 = n0 + 16;

    const float a0 = coords[n0 * 3], a1 = coords[n0 * 3 + 1], a2 = coords[n0 * 3 + 2];
    const float b0 = coords[n1 * 3], b1 = coords[n1 * 3 + 1], b2 = coords[n1 * 3 + 2];

    // ---- g rows directly: r = 16*tau + 4*g + j, 3 FMA each ----
    float ga[16], gb[16];
#pragma unroll
    for (int i = 0; i < 16; i++) {
        const int r = ((i >> 2) << 4) + 4 * g + (i & 3);
        const float m0 = s_M1[r * 3], m1 = s_M1[r * 3 + 1], m2 = s_M1[r * 3 + 2];
        const float bb = s_b1p[r];
        ga[i] = bb + a0 * m0 + a1 * m1 + a2 * m2;
        gb[i] = bb + b0 * m0 + b1 * m1 + b2 * m2;
    }

    // ---- LayerNorm over 64 rows (cross-lane over g groups) ----
    float s1a = 0.f, s1b = 0.f;
#pragma unroll
    for (int i = 0; i < 16; i++) { s1a += ga[i]; s1b += gb[i]; }
    s1a += __shfl_xor(s1a, 16, 64); s1a += __shfl_xor(s1a, 32, 64);
    s1b += __shfl_xor(s1b, 16, 64); s1b += __shfl_xor(s1b, 32, 64);
    const float mu0 = s1a * (1.f / 64.f), mu1 = s1b * (1.f / 64.f);
    float s2a = 0.f, s2b = 0.f;
#pragma unroll
    for (int i = 0; i < 16; i++) {
        const float d0 = ga[i] - mu0; s2a += d0 * d0;
        const float d1 = gb[i] - mu1; s2b += d1 * d1;
    }
    s2a += __shfl_xor(s2a, 16, 64); s2a += __shfl_xor(s2a, 32, 64);
    s2b += __shfl_xor(s2b, 16, 64); s2b += __shfl_xor(s2b, 32, 64);
    const float rs0 = rsqrtf(s2a * (1.f / 64.f) + 1e-5f);
    const float rs1 = rsqrtf(s2b * (1.f / 64.f) + 1e-5f);

    // ---- gn + hi/lo split + pack into B-frags ----
    BFrag Gh0[2], Gl0[2], Gh1[2], Gl1[2];
#pragma unroll
    for (int ks = 0; ks < 2; ks++) {
#pragma unroll
        for (int q = 0; q < 4; q++) {
            const int i0 = ks * 8 + 2 * q, i1 = i0 + 1;
            const int r0 = ((i0 >> 2) << 4) + 4 * g + (i0 & 3);
            const int r1 = ((i1 >> 2) << 4) + 4 * g + (i1 & 3);
            const float gnA0 = (ga[i0] - mu0) * rs0 * s_lng[r0] + s_lnb[r0];
            const float gnA1 = (ga[i1] - mu0) * rs0 * s_lng[r1] + s_lnb[r1];
            const float gnB0 = (gb[i0] - mu1) * rs1 * s_lng[r0] + s_lnb[r0];
            const float gnB1 = (gb[i1] - mu1) * rs1 * s_lng[r1] + s_lnb[r1];
            const unsigned short hA0 = f2bf_hw(gnA0), hA1 = f2bf_hw(gnA1);
            const unsigned short hB0 = f2bf_hw(gnB0), hB1 = f2bf_hw(gnB1);
            Gh0[ks].u[q] = pk2b(hA0, hA1);
            Gl0[ks].u[q] = cpack(gnA0 - bf2f(hA0), gnA1 - bf2f(hA1));
            Gh1[ks].u[q] = pk2b(hB0, hB1);
            Gl1[ks].u[q] = cpack(gnB0 - bf2f(hB0), gnB1 - bf2f(hB1));
        }
    }

    // ---- logits = gw2 @ gn via 3-term MFMA (two independent chains) ----
    f4v lacc0 = {0.f, 0.f, 0.f, 0.f}, lacc1 = {0.f, 0.f, 0.f, 0.f};
    {
        BFrag W0, W1, V0, V1;
        W0.q = sW2H[0 * 64 + lane]; W1.q = sW2H[1 * 64 + lane];
        V0.q = sW2L[0 * 64 + lane]; V1.q = sW2L[1 * 64 + lane];
        lacc0 = __builtin_amdgcn_mfma_f32_16x16x32_bf16(W0.s, Gh0[0].s, lacc0, 0, 0, 0);
        lacc1 = __builtin_amdgcn_mfma_f32_16x16x32_bf16(W0.s, Gh1[0].s, lacc1, 0, 0, 0);
        lacc0 = __builtin_amdgcn_mfma_f32_16x16x32_bf16(W1.s, Gh0[1].s, lacc0, 0, 0, 0);
        lacc1 = __builtin_amdgcn_mfma_f32_16x16x32_bf16(W1.s, Gh1[1].s, lacc1, 0, 0, 0);
        lacc0 = __builtin_amdgcn_mfma_f32_16x16x32_bf16(W0.s, Gl0[0].s, lacc0, 0, 0, 0);
        lacc1 = __builtin_amdgcn_mfma_f32_16x16x32_bf16(W0.s, Gl1[0].s, lacc1, 0, 0, 0);
        lacc0 = __builtin_amdgcn_mfma_f32_16x16x32_bf16(W1.s, Gl0[1].s, lacc0, 0, 0, 0);
        lacc1 = __builtin_amdgcn_mfma_f32_16x16x32_bf16(W1.s, Gl1[1].s, lacc1, 0, 0, 0);
        lacc0 = __builtin_amdgcn_mfma_f32_16x16x32_bf16(V0.s, Gh0[0].s, lacc0, 0, 0, 0);
        lacc1 = __builtin_amdgcn_mfma_f32_16x16x32_bf16(V0.s, Gh1[0].s, lacc1, 0, 0, 0);
        lacc0 = __builtin_amdgcn_mfma_f32_16x16x32_bf16(V1.s, Gh0[1].s, lacc0, 0, 0, 0);
        lacc1 = __builtin_amdgcn_mfma_f32_16x16x32_bf16(V1.s, Gh1[1].s, lacc1, 0, 0, 0);
    }

    float logit0[8], logit1[8];
#pragma unroll
    for (int j = 0; j < 4; j++) {
        const float o0 = __shfl_xor(lacc0[j], 16, 64);
        const float o1 = __shfl_xor(lacc1[j], 16, 64);
        logit0[j] = lacc0[j] + s_gb2[j];
        logit0[4 + j] = o0 + s_gb2[4 + j];
        logit1[j] = lacc1[j] + s_gb2[j];
        logit1[4 + j] = o1 + s_gb2[4 + j];
    }

    // ---- top-2 + margin flag (per point) ----
    unsigned mbits0 = 0, mbits1 = 0;
    bool flg0, flg1;
    {
        float m1 = logit0[0]; int i1 = 0;
#pragma unroll
        for (int e = 1; e < 8; e++) if (logit0[e] > m1) { m1 = logit0[e]; i1 = e; }
        float m2 = -INFINITY; int i2 = -1;
#pragma unroll
        for (int e = 0; e < 8; e++) if (e != i1 && logit0[e] > m2) { m2 = logit0[e]; i2 = e; }
        float m3 = -INFINITY;
#pragma unroll
        for (int e = 0; e < 8; e++) if (e != i1 && e != i2 && logit0[e] > m3) m3 = logit0[e];
#pragma unroll
        for (int e = 0; e < 8; e++) if (logit0[e] >= m2) mbits0 |= 1u << e;
        flg0 = (m2 - m3 < TAU);
    }
    {
        float m1 = logit1[0]; int i1 = 0;
#pragma unroll
        for (int e = 1; e < 8; e++) if (logit1[e] > m1) { m1 = logit1[e]; i1 = e; }
        float m2 = -INFINITY; int i2 = -1;
#pragma unroll
        for (int e = 0; e < 8; e++) if (e != i1 && logit1[e] > m2) { m2 = logit1[e]; i2 = e; }
        float m3 = -INFINITY;
#pragma unroll
        for (int e = 0; e < 8; e++) if (e != i1 && e != i2 && logit1[e] > m3) m3 = logit1[e];
#pragma unroll
        for (int e = 0; e < 8; e++) if (logit1[e] >= m2) mbits1 |= 1u << e;
        flg1 = (m2 - m3 < TAU);
    }

    const bool active = (g == 0);
    if (active) { sel[n0] = (unsigned char)mbits0; sel[n1] = (unsigned char)mbits1; }

#pragma unroll
    for (int e = 0; e < 8; e++) {
        const unsigned long long bal0 = __ballot(active && ((mbits0 >> e) & 1u));
        const unsigned long long bal1 = __ballot(active && ((mbits1 >> e) & 1u));
        if (lane == 0) atomicAdd(&s_cnt[e], (int)(__popcll(bal0) + __popcll(bal1)));
    }
    {
        const unsigned long long bal0 = __ballot(active && flg0);
        const unsigned long long bal1 = __ballot(active && flg1);
        const int p0 = (int)__popcll(bal0);
        int pos0 = 0;
        if (lane == 0 && (bal0 | bal1)) pos0 = atomicAdd(refcnt, p0 + (int)__popcll(bal1));
        pos0 = __shfl(pos0, 0, 64);
        if (active && flg0) {
            const int rank = (int)__popcll(bal0 & ((1ull << lane) - 1ull));
            reflist[pos0 + rank] = n0;
        }
        if (active && flg1) {
            const int rank = p0 + (int)__popcll(bal1 & ((1ull << lane) - 1ull));
            reflist[pos0 + rank] = n1;
        }
    }
    __syncthreads();
    if (t < 8) blkcnt[blockIdx.x * 8 + t] = s_cnt[t];
}

// ---------------- K1.25: exact-fp32 refine + fused last-block scan ----------------
__global__ __launch_bounds__(256) void refine_kernel(
    const float* __restrict__ coords,
    const float* __restrict__ fw, const float* __restrict__ fb,
    const float* __restrict__ gw1, const float* __restrict__ gb1,
    const float* __restrict__ lng, const float* __restrict__ lnb,
    const float* __restrict__ gw2, const float* __restrict__ gb2,
    const int* __restrict__ reflist, const int* __restrict__ refcnt,
    unsigned char* __restrict__ sel, int* __restrict__ blkcnt,
    int* __restrict__ baseoff, int* __restrict__ counts, int* __restrict__ rs_done)
{
    __shared__ float s_gw1t[64 * 65];           // transposed + pad
    __shared__ float s_gw2[512];
    __shared__ float s_fw[192], s_fb[64], s_gb1[64], s_lng[64], s_lnb[64], s_gb2[8];
    __shared__ float s_f[4][64];
    __shared__ int s_ticket;
    __shared__ int s_wsc[4];

    const int t = threadIdx.x;
    const int wv = t >> 6, lane = t & 63;
    const int R = *refcnt;

    if (R > 0 && blockIdx.x * 4 < R) {          // block-uniform
        for (int i = t; i < 4096; i += 256) s_gw1t[(i & 63) * 65 + (i >> 6)] = gw1[i];
        for (int i = t; i < 512; i += 256) s_gw2[i] = gw2[i];
        if (t < 192) s_fw[t] = fw[t];
        if (t < 64) { s_fb[t] = fb[t]; s_gb1[t] = gb1[t]; s_lng[t] = lng[t]; s_lnb[t] = lnb[t]; }
        if (t < 8) s_gb2[t] = gb2[t];
        __syncthreads();

        for (int idx = blockIdx.x * 4 + wv; idx < R; idx += gridDim.x * 4) {
            const int n = reflist[idx];
            const float c0 = coords[n * 3], c1 = coords[n * 3 + 1], c2 = coords[n * 3 + 2];
            const float fr = s_fb[lane] + c0 * s_fw[lane * 3] + c1 * s_fw[lane * 3 + 1]
                           + c2 * s_fw[lane * 3 + 2];
            s_f[wv][lane] = fr;
            float a = s_gb1[lane];
#pragma unroll
            for (int k = 0; k < 64; k++)
                a += s_f[wv][k] * s_gw1t[k * 65 + lane];
            float mu = a;
#pragma unroll
            for (int d = 1; d < 64; d <<= 1) mu += __shfl_xor(mu, d, 64);
            mu *= (1.f / 64.f);
            const float dv = a - mu;
            float v = dv * dv;
#pragma unroll
            for (int d = 1; d < 64; d <<= 1) v += __shfl_xor(v, d, 64);
            const float rs = rsqrtf(v * (1.f / 64.f) + 1e-5f);
            const float gn = dv * rs * s_lng[lane] + s_lnb[lane];
            float lp[8];
#pragma unroll
            for (int e = 0; e < 8; e++) lp[e] = gn * s_gw2[e * 64 + lane];
#pragma unroll
            for (int e = 0; e < 8; e++) {
#pragma unroll
                for (int d = 1; d < 64; d <<= 1) lp[e] += __shfl_xor(lp[e], d, 64);
                lp[e] += s_gb2[e];
            }
            if (lane == 0) {
                float m1 = lp[0]; int i1 = 0;
#pragma unroll
                for (int e = 1; e < 8; e++) if (lp[e] > m1) { m1 = lp[e]; i1 = e; }
                float m2 = -INFINITY;
#pragma unroll
                for (int e = 0; e < 8; e++) if (e != i1 && lp[e] > m2) m2 = lp[e];
                unsigned mbits = 0;
#pragma unroll
                for (int e = 0; e < 8; e++) if (lp[e] >= m2) mbits |= 1u << e;
                const unsigned old = sel[n];
                if (mbits != old) {
                    sel[n] = (unsigned char)mbits;
                    const int b = n >> 7;
#pragma unroll
                    for (int e = 0; e < 8; e++) {
                        const int was = (old >> e) & 1, now = (mbits >> e) & 1;
                        if (was != now) atomicAdd(&blkcnt[b * 8 + e], now - was);
                    }
                }
            }
        }
    }

    // ---- done protocol; last block runs the scan ----
    __threadfence();
    __syncthreads();
    if (t == 0) s_ticket = atomicAdd(rs_done, 1);
    __syncthreads();
    if (s_ticket == (int)gridDim.x - 1) {
        __threadfence();
        for (int e = 0; e < 8; e++) {
            int v[8]; int sum = 0;
#pragma unroll
            for (int i = 0; i < 8; i++) { v[i] = blkcnt[(t * 8 + i) * 8 + e]; sum += v[i]; }
            int incl = sum;
#pragma unroll
            for (int d = 1; d < 64; d <<= 1) {
                const int x = __shfl_up(incl, d, 64);
                if (lane >= d) incl += x;
            }
            if (lane == 63) s_wsc[wv] = incl;
            __syncthreads();
            int woff = 0;
#pragma unroll
            for (int i = 0; i < 4; i++) if (i < wv) woff += s_wsc[i];
            int run = woff + incl - sum;
#pragma unroll
            for (int i = 0; i < 8; i++) { baseoff[(t * 8 + i) * 8 + e] = run; run += v[i]; }
            if (t == 255) counts[e] = run;
            __syncthreads();
        }
    }
}

// ---------------- K2: scatter + aux ----------------
__global__ __launch_bounds__(128) void scatter_kernel(
    const unsigned char* __restrict__ sel, const int* __restrict__ baseoff,
    const int* __restrict__ counts, int* __restrict__ buckets, float* __restrict__ out)
{
    __shared__ int s_w0[8];
    const int t = threadIdx.x;
    const int n = blockIdx.x * 128 + t;
    if (blockIdx.x == 0 && t == 0) {
        double s = 0.0;
        for (int e = 0; e < 8; e++) { const double c = (double)counts[e]; s += c * c; }
        out[NPTS] = (float)(8.0 * s / ((double)NPTS * (double)NPTS));
    }
    const unsigned m = sel[n];
    const int w = t >> 6, lane = t & 63;
    unsigned long long bal[8];
#pragma unroll
    for (int e = 0; e < 8; e++) {
        bal[e] = __ballot((m >> e) & 1u);
        if (w == 0 && lane == 0) s_w0[e] = (int)__popcll(bal[e]);
    }
    __syncthreads();
#pragma unroll
    for (int e = 0; e < 8; e++) {
        if ((m >> e) & 1u) {
            int rank = (int)__popcll(bal[e] & ((1ull << lane) - 1ull));
            if (w == 1) rank += s_w0[e];
            buckets[e * NPTS + baseoff[blockIdx.x * 8 + e] + rank] = n;
        }
    }
}

// ---------------- K3: per-expert MFMA SIREN; 2 chains/wave; compact vchunk grid ----------------
__global__ __launch_bounds__(256) void expert_kernel(
    const float* __restrict__ coords,
    const float* __restrict__ M0, const float* __restrict__ b0p,
    const float* __restrict__ wl, const float* __restrict__ bl,
    const uint4* __restrict__ packA, const float* __restrict__ biasS,
    const int* __restrict__ counts, const int* __restrict__ buckets,
    float* __restrict__ out)
{
    __shared__ float s_b[192];
    __shared__ float s_wl[64];
    __shared__ float s_M0[192];
    __shared__ float s_b0p[64];
    __shared__ float s_bl;

    const int t = threadIdx.x;
    // prefix over ceil(counts[e]/128) — scalar, unrolled (no runtime-indexed reg arrays)
    const int c0n = (counts[0] + 127) >> 7;
    const int c1n = (counts[1] + 127) >> 7;
    const int c2n = (counts[2] + 127) >> 7;
    const int c3n = (counts[3] + 127) >> 7;
    const int c4n = (counts[4] + 127) >> 7;
    const int c5n = (counts[5] + 127) >> 7;
    const int c6n = (counts[6] + 127) >> 7;
    const int c7n = (counts[7] + 127) >> 7;
    const int p1 = c0n, p2 = p1 + c1n, p3 = p2 + c2n, p4 = p3 + c3n;
    const int p5 = p4 + c4n, p6 = p5 + c5n, p7 = p6 + c6n, total = p7 + c7n;

    bool first = true;
    for (int vc = blockIdx.x; vc < total; vc += gridDim.x) {
        int e = 0, pe = 0;
        if (vc >= p1) { e = 1; pe = p1; }
        if (vc >= p2) { e = 2; pe = p2; }
        if (vc >= p3) { e = 3; pe = p3; }
        if (vc >= p4) { e = 4; pe = p4; }
        if (vc >= p5) { e = 5; pe = p5; }
        if (vc >= p6) { e = 6; pe = p6; }
        if (vc >= p7) { e = 7; pe = p7; }
        const int cnt = counts[e];
        const int base = (vc - pe) * 128;

        if (!first) __syncthreads();
        first = false;
        if (t < 192) { s_b[t] = biasS[e * 192 + t]; s_M0[t] = M0[e * 192 + t]; }
        if (t < 64) { s_b0p[t] = b0p[e * 64 + t]; s_wl[t] = wl[e * 64 + t]; }
        if (t == 0) s_bl = bl[e];
        __syncthreads();

        const int lane = t & 63;
        const int wv = t >> 6;
        const int g = lane >> 4, c = lane & 15;
        const int i0 = base + wv * 32 + c;
        const int i1 = i0 + 16;
        const int id0 = (i0 < cnt) ? buckets[e * NPTS + i0] : -1;
        const int id1 = (i1 < cnt) ? buckets[e * NPTS + i1] : -1;

        const float a0 = (id0 >= 0) ? coords[id0 * 3] : 0.f;
        const float a1 = (id0 >= 0) ? coords[id0 * 3 + 1] : 0.f;
        const float a2 = (id0 >= 0) ? coords[id0 * 3 + 2] : 0.f;
        const float b0 = (id1 >= 0) ? coords[id1 * 3] : 0.f;
        const float b1 = (id1 >= 0) ? coords[id1 * 3 + 1] : 0.f;
        const float b2 = (id1 >= 0) ? coords[id1 * 3 + 2] : 0.f;

        // ---- layer 0 folded: z0[r] = b0p[r] + M0[r]·c in D layout ----
        f4v acc0[4], acc1[4];
#pragma unroll
        for (int tau = 0; tau < 4; tau++) {
#pragma unroll
            for (int j = 0; j < 4; j++) {
                const int r = tau * 16 + 4 * g + j;
                const float m0 = s_M0[r * 3], m1 = s_M0[r * 3 + 1], m2 = s_M0[r * 3 + 2];
                const float bb = s_b0p[r];
                acc0[tau][j] = bb + a0 * m0 + a1 * m1 + a2 * m2;
                acc1[tau][j] = bb + b0 * m0 + b1 * m1 + b2 * m2;
            }
        }

        // ---- sin + repack -> layer-1 B fragments ----
        BFrag B0[2], B1[2];
#pragma unroll
        for (int ks = 0; ks < 2; ks++) {
            B0[ks].u[0] = cpack(sinrev(acc0[2 * ks][0]), sinrev(acc0[2 * ks][1]));
            B0[ks].u[1] = cpack(sinrev(acc0[2 * ks][2]), sinrev(acc0[2 * ks][3]));
            B0[ks].u[2] = cpack(sinrev(acc0[2 * ks + 1][0]), sinrev(acc0[2 * ks + 1][1]));
            B0[ks].u[3] = cpack(sinrev(acc0[2 * ks + 1][2]), sinrev(acc0[2 * ks + 1][3]));
            B1[ks].u[0] = cpack(sinrev(acc1[2 * ks][0]), sinrev(acc1[2 * ks][1]));
            B1[ks].u[1] = cpack(sinrev(acc1[2 * ks][2]), sinrev(acc1[2 * ks][3]));
            B1[ks].u[2] = cpack(sinrev(acc1[2 * ks + 1][0]), sinrev(acc1[2 * ks + 1][1]));
            B1[ks].u[3] = cpack(sinrev(acc1[2 * ks + 1][2]), sinrev(acc1[2 * ks + 1][3]));
        }

        // ---- layer 1 (MFMA) ----
        {
#pragma unroll
            for (int tau = 0; tau < 4; tau++) {
                const float4 b = *(const float4*)&s_b[64 + tau * 16 + 4 * g];
                acc0[tau][0] = b.x; acc0[tau][1] = b.y; acc0[tau][2] = b.z; acc0[tau][3] = b.w;
                acc1[tau][0] = b.x; acc1[tau][1] = b.y; acc1[tau][2] = b.z; acc1[tau][3] = b.w;
            }
            const uint4* Ab = packA + (size_t)((e * 3 + 1) * 8) * 64 + lane;
#pragma unroll
            for (int tau = 0; tau < 4; tau++) {
                BFrag A0, A1;
                A0.q = Ab[(tau * 2 + 0) * 64];
                A1.q = Ab[(tau * 2 + 1) * 64];
                acc0[tau] = __builtin_amdgcn_mfma_f32_16x16x32_bf16(A0.s, B0[0].s, acc0[tau], 0, 0, 0);
                acc0[tau] = __builtin_amdgcn_mfma_f32_16x16x32_bf16(A1.s, B0[1].s, acc0[tau], 0, 0, 0);
                acc1[tau] = __builtin_amdgcn_mfma_f32_16x16x32_bf16(A0.s, B1[0].s, acc1[tau], 0, 0, 0);
                acc1[tau] = __builtin_amdgcn_mfma_f32_16x16x32_bf16(A1.s, B1[1].s, acc1[tau], 0, 0, 0);
            }
#pragma unroll
            for (int ks = 0; ks < 2; ks++) {
                B0[ks].u[0] = cpack(sinrev(acc0[2 * ks][0]), sinrev(acc0[2 * ks][1]));
                B0[ks].u[1] = cpack(sinrev(acc0[2 * ks][2]), sinrev(acc0[2 * ks][3]));
                B0[ks].u[2] = cpack(sinrev(acc0[2 * ks + 1][0]), sinrev(acc0[2 * ks + 1][1]));
                B0[ks].u[3] = cpack(sinrev(acc0[2 * ks + 1][2]), sinrev(acc0[2 * ks + 1][3]));
                B1[ks].u[0] = cpack(sinrev(acc1[2 * ks][0]), sinrev(acc1[2 * ks][1]));
                B1[ks].u[1] = cpack(sinrev(acc1[2 * ks][2]), sinrev(acc1[2 * ks][3]));
                B1[ks].u[2] = cpack(sinrev(acc1[2 * ks + 1][0]), sinrev(acc1[2 * ks + 1][1]));
                B1[ks].u[3] = cpack(sinrev(acc1[2 * ks + 1][2]), sinrev(acc1[2 * ks + 1][3]));
            }
        }

        // ---- layer 2 + final dot ----
        {
#pragma unroll
            for (int tau = 0; tau < 4; tau++) {
                const float4 b = *(const float4*)&s_b[128 + tau * 16 + 4 * g];
                acc0[tau][0] = b.x; acc0[tau][1] = b.y; acc0[tau][2] = b.z; acc0[tau][3] = b.w;
                acc1[tau][0] = b.x; acc1[tau][1] = b.y; acc1[tau][2] = b.z; acc1[tau][3] = b.w;
            }
            const uint4* Ab = packA + (size_t)((e * 3 + 2) * 8) * 64 + lane;
#pragma unroll
            for (int tau = 0; tau < 4; tau++) {
                BFrag A0, A1;
                A0.q = Ab[(tau * 2 + 0) * 64];
                A1.q = Ab[(tau * 2 + 1) * 64];
                acc0[tau] = __builtin_amdgcn_mfma_f32_16x16x32_bf16(A0.s, B0[0].s, acc0[tau], 0, 0, 0);
                acc0[tau] = __builtin_amdgcn_mfma_f32_16x16x32_bf16(A1.s, B0[1].s, acc0[tau], 0, 0, 0);
                acc1[tau] = __builtin_amdgcn_mfma_f32_16x16x32_bf16(A0.s, B1[0].s, acc1[tau], 0, 0, 0);
                acc1[tau] = __builtin_amdgcn_mfma_f32_16x16x32_bf16(A1.s, B1[1].s, acc1[tau], 0, 0, 0);
            }
            float px0 = 0.f, px1 = 0.f;
#pragma unroll
            for (int tau = 0; tau < 4; tau++) {
                const float4 w = *(const float4*)&s_wl[tau * 16 + 4 * g];
                px0 += sinrev(acc0[tau][0]) * w.x + sinrev(acc0[tau][1]) * w.y
                     + sinrev(acc0[tau][2]) * w.z + sinrev(acc0[tau][3]) * w.w;
                px1 += sinrev(acc1[tau][0]) * w.x + sinrev(acc1[tau][1]) * w.y
                     + sinrev(acc1[tau][2]) * w.z + sinrev(acc1[tau][3]) * w.w;
            }
            px0 += __shfl_xor(px0, 16, 64); px0 += __shfl_xor(px0, 32, 64);
            px1 += __shfl_xor(px1, 16, 64); px1 += __shfl_xor(px1, 32, 64);
            if (g == 0) {
                if (id0 >= 0) atomicAdd(&out[id0], px0 + s_bl);
                if (id1 >= 0) atomicAdd(&out[id1], px1 + s_bl);
            }
        }
    }
}

extern "C" void kernel_launch(void* const* d_in, const int* in_sizes, int n_in,
                              void* d_out, int out_size, void* d_ws, size_t ws_size,
                              hipStream_t stream)
{
    const float* coords = (const float*)d_in[0];
    const float* fw  = (const float*)d_in[1];
    const float* fb  = (const float*)d_in[2];
    const float* gw1 = (const float*)d_in[3];
    const float* gb1 = (const float*)d_in[4];
    const float* lng = (const float*)d_in[5];
    const float* lnb = (const float*)d_in[6];
    const float* gw2 = (const float*)d_in[7];
    const float* gb2 = (const float*)d_in[8];
    const float* we0 = (const float*)d_in[9];
    const float* be0 = (const float*)d_in[10];
    const float* wm  = (const float*)d_in[11];
    const float* bm  = (const float*)d_in[12];
    const float* wl  = (const float*)d_in[13];
    const float* bl  = (const float*)d_in[14];
    float* out = (float*)d_out;

    char* ws = (char*)d_ws;
    int* counts           = (int*)ws;                        // 64
    int* buckets          = (int*)(ws + 64);                 // 8*NPTS*4 = 8388608
    uint4* packA          = (uint4*)(ws + 8388672);          // 196608
    float* biasS          = (float*)(ws + 8585280);          // 6144
    int* blkcnt           = (int*)(ws + 8591424);            // 65536
    int* baseoff          = (int*)(ws + 8656960);            // 65536
    unsigned char* sel    = (unsigned char*)(ws + 8722496);  // 262144
    uint4* packGW2H       = (uint4*)(ws + 8984640);          // 2048
    uint4* packGW2L       = (uint4*)(ws + 8986688);          // 2048
    int* reflist          = (int*)(ws + 8988736);            // 1048576
    int* refcnt           = (int*)(ws + 10037312);           // 64
    float* M1             = (float*)(ws + 10037376);         // 768
    float* b1p            = (float*)(ws + 10038144);         // 256
    float* M0             = (float*)(ws + 10038400);         // 6144
    float* b0p            = (float*)(ws + 10044544);         // 2048
    int* rs_done          = (int*)(ws + 10046592);           // 64

    prep_kernel<<<64, 256, 0, stream>>>(we0, be0, wm, bm, gw1, gw2, fw, fb, gb1,
                                        packA, biasS, packGW2H, packGW2L, M1, b1p,
                                        M0, b0p, refcnt, rs_done);
    gate_kernel<<<GBLK, 256, 0, stream>>>(coords, M1, b1p, lng, lnb, gb2,
                                          packGW2H, packGW2L,
                                          sel, blkcnt, reflist, refcnt, out);
    refine_kernel<<<256, 256, 0, stream>>>(coords, fw, fb, gw1, gb1, lng, lnb, gw2, gb2,
                                           reflist, refcnt, sel, blkcnt,
                                           baseoff, counts, rs_done);
    scatter_kernel<<<GBLK, 128, 0, stream>>>(sel, baseoff, counts, buckets, out);
    expert_kernel<<<2056, 256, 0, stream>>>(coords, M0, b0p, wl, bl, packA, biasS,
                                            counts, buckets, out);
}

// Round 18
// 85.782 us; speedup vs baseline: 1.3458x; 1.3458x over previous
//
#include <hip/hip_runtime.h>
#include <math.h>

#define NPTS 262144
#define GBLK (NPTS / 128)     // 2048 gate blocks / 128-pt groups
#define TAU  0.01f            // refine margin threshold (logit units)

typedef float f4v __attribute__((ext_vector_type(4)));
typedef short s8v __attribute__((ext_vector_type(8)));

// manual RNE (prep only; identical rounding to HW cvt)
static __device__ __forceinline__ unsigned short f2bf(float f) {
    unsigned u = __float_as_uint(f);
    u += 0x7fffu + ((u >> 16) & 1u);
    return (unsigned short)(u >> 16);
}
// HW bf16 convert (clang lowers paired fptrunc to v_cvt_pk_bf16_f32, RNE)
static __device__ __forceinline__ unsigned short f2bf_hw(float f) {
    __bf16 b = (__bf16)f;
    unsigned short u;
    __builtin_memcpy(&u, &b, 2);
    return u;
}
static __device__ __forceinline__ float bf2f(unsigned short h) {
    return __uint_as_float(((unsigned)h) << 16);
}
static __device__ __forceinline__ unsigned pk2b(unsigned short lo, unsigned short hi) {
    return ((unsigned)hi << 16) | (unsigned)lo;
}
static __device__ __forceinline__ unsigned cpack(float lo, float hi) {
    return pk2b(f2bf_hw(lo), f2bf_hw(hi));
}
static __device__ __forceinline__ float sinrev(float x) {   // sin(2*pi*x)
    return __builtin_amdgcn_sinf(x);
}

union BFrag { uint4 q; unsigned u[4]; s8v s; };

// ---- prep: expert A-frags + biases + gw2 packs + folded gate M1/b1' + folded expert M0e/b0e' ----
__global__ __launch_bounds__(256) void prep_kernel(
    const float* __restrict__ we0, const float* __restrict__ be0,
    const float* __restrict__ wm, const float* __restrict__ bm,
    const float* __restrict__ gw1, const float* __restrict__ gw2,
    const float* __restrict__ fw, const float* __restrict__ fb,
    const float* __restrict__ gb1,
    uint4* __restrict__ packA, float* __restrict__ biasS,
    uint4* __restrict__ packGW2H, uint4* __restrict__ packGW2L,
    float* __restrict__ M1, float* __restrict__ b1p,
    float* __restrict__ M0, float* __restrict__ b0p, int* __restrict__ refcnt)
{
    const int idx = blockIdx.x * 256 + threadIdx.x;
    const float PI2I = 0.15915494309189535f;
    if (idx < 12288) {
        const int l = idx & 63;
        const int fr = (idx >> 6) & 7;
        const int grp = idx >> 9;            // e*3 + ell
        const int e = grp / 3, ell = grp % 3;
        const int tau = fr >> 1, ks = fr & 1;
        const int g = l >> 4, m = l & 15;
        const int row = tau * 16 + m;
        const float scale = (ell == 0) ? (22.5f + 45.0f * (float)e) * PI2I : 30.0f * PI2I;
        const float* W = (ell == 0) ? (we0 + e * 4096) : (wm + ((ell - 1) * 8 + e) * 4096);
        unsigned short v[8];
#pragma unroll
        for (int i = 0; i < 8; i++) {
            const int k = 32 * ks + 4 * g + (i < 4 ? i : i + 12);
            v[i] = f2bf(W[row * 64 + k] * scale);
        }
        uint4 q;
        q.x = pk2b(v[0], v[1]); q.y = pk2b(v[2], v[3]);
        q.z = pk2b(v[4], v[5]); q.w = pk2b(v[6], v[7]);
        packA[idx] = q;
    } else if (idx < 13824) {
        const int j = idx - 12288;           // e*192 + ell*64 + r
        const int r = j & 63;
        const int grp = j >> 6;
        const int e = grp / 3, ell = grp % 3;
        const float scale = (ell == 0) ? (22.5f + 45.0f * (float)e) * PI2I : 30.0f * PI2I;
        const float b = (ell == 0) ? be0[e * 64 + r] : bm[((ell - 1) * 8 + e) * 64 + r];
        biasS[j] = b * scale;
    } else if (idx < 13952) {
        // gate gw2 hi/lo A-frags: rows 0..7 = gw2, rows 8..15 = 0; 2 frags (ks) x 64 lanes
        const int j = idx - 13824;           // 0..127
        const int l = j & 63;
        const int ks = j >> 6;
        const int g = l >> 4;
        const int row = l & 15;
        unsigned short vh[8], vl[8];
#pragma unroll
        for (int i = 0; i < 8; i++) {
            const int k = 32 * ks + 4 * g + (i < 4 ? i : i + 12);
            const float x = (row < 8) ? gw2[row * 64 + k] : 0.f;
            const unsigned short h = f2bf(x);
            vh[i] = h;
            vl[i] = f2bf(x - bf2f(h));
        }
        uint4 qh, ql;
        qh.x = pk2b(vh[0], vh[1]); qh.y = pk2b(vh[2], vh[3]);
        qh.z = pk2b(vh[4], vh[5]); qh.w = pk2b(vh[6], vh[7]);
        ql.x = pk2b(vl[0], vl[1]); ql.y = pk2b(vl[2], vl[3]);
        ql.z = pk2b(vl[4], vl[5]); ql.w = pk2b(vl[6], vl[7]);
        packGW2H[j] = qh; packGW2L[j] = ql;
    } else if (idx < 14144) {
        // M1 = gw1 @ fw  (64x3), fp64 accumulate
        const int m = idx - 13952;           // 0..191
        const int r = m / 3, d = m % 3;
        double s = 0.0;
        for (int j = 0; j < 64; j++) s += (double)gw1[r * 64 + j] * (double)fw[j * 3 + d];
        M1[m] = (float)s;
    } else if (idx < 14208) {
        // b1' = gw1 @ fb + gb1
        const int r = idx - 14144;           // 0..63
        double s = (double)gb1[r];
        for (int j = 0; j < 64; j++) s += (double)gw1[r * 64 + j] * (double)fb[j];
        b1p[r] = (float)s;
    } else if (idx < 15744) {
        // M0e = scale_e * (we0[e] @ fw)  (8 x 64 x 3), fp64 accumulate
        const int m = idx - 14208;           // 0..1535
        const int e = m / 192;
        const int rem = m % 192;
        const int r = rem / 3, d = rem % 3;
        const double scale = (22.5 + 45.0 * (double)e) * 0.15915494309189535;
        double s = 0.0;
        for (int j = 0; j < 64; j++) s += (double)we0[e * 4096 + r * 64 + j] * (double)fw[j * 3 + d];
        M0[m] = (float)(s * scale);
    } else if (idx < 16256) {
        // b0e' = scale_e * (we0[e] @ fb + be0[e])  (8 x 64)
        const int m = idx - 15744;           // 0..511
        const int e = m >> 6, r = m & 63;
        const double scale = (22.5 + 45.0 * (double)e) * 0.15915494309189535;
        double s = (double)be0[e * 64 + r];
        for (int j = 0; j < 64; j++) s += (double)we0[e * 4096 + r * 64 + j] * (double)fb[j];
        b0p[m] = (float)(s * scale);
    } else if (idx == 16256) {
        *refcnt = 0;
    }
}

// ---------------- K1: gate — folded stage-1 (3 FMA/row) + MFMA stage-2 (hi/lo); zeroes out[] ----------------
// 256 threads = 4 waves x 32 points = 128 points per block.
__global__ __launch_bounds__(256) void gate_kernel(
    const float* __restrict__ coords,
    const float* __restrict__ M1, const float* __restrict__ b1p,
    const float* __restrict__ lng, const float* __restrict__ lnb,
    const float* __restrict__ gb2,
    const uint4* __restrict__ packGW2H, const uint4* __restrict__ packGW2L,
    unsigned char* __restrict__ sel, int* __restrict__ blkcnt,
    int* __restrict__ reflist, int* __restrict__ refcnt, float* __restrict__ out)
{
    __shared__ float s_M1[192], s_b1p[64], s_lng[64], s_lnb[64], s_gb2[8];
    __shared__ uint4 sW2H[128], sW2L[128];      // 4 KB
    __shared__ int s_cnt[8];
    const int t = threadIdx.x;
    if (t < 128) { sW2H[t] = packGW2H[t]; sW2L[t] = packGW2L[t]; }
    if (t < 192) s_M1[t] = M1[t];
    if (t < 64) { s_b1p[t] = b1p[t]; s_lng[t] = lng[t]; s_lnb[t] = lnb[t]; }
    if (t < 8) { s_gb2[t] = gb2[t]; s_cnt[t] = 0; }
    if (t < 128) out[blockIdx.x * 128 + t] = 0.f;
    __syncthreads();

    const int lane = t & 63;
    const int wv = t >> 6;
    const int g = lane >> 4, c = lane & 15;
    const int n0 = blockIdx.x * 128 + wv * 32 + c;
    const int n1 = n0 + 16;

    const float a0 = coords[n0 * 3], a1 = coords[n0 * 3 + 1], a2 = coords[n0 * 3 + 2];
    const float b0 = coords[n1 * 3], b1 = coords[n1 * 3 + 1], b2 = coords[n1 * 3 + 2];

    // ---- g rows directly: r = 16*tau + 4*g + j, 3 FMA each ----
    float ga[16], gb[16];
#pragma unroll
    for (int i = 0; i < 16; i++) {
        const int r = ((i >> 2) << 4) + 4 * g + (i & 3);
        const float m0 = s_M1[r * 3], m1 = s_M1[r * 3 + 1], m2 = s_M1[r * 3 + 2];
        const float bb = s_b1p[r];
        ga[i] = bb + a0 * m0 + a1 * m1 + a2 * m2;
        gb[i] = bb + b0 * m0 + b1 * m1 + b2 * m2;
    }

    // ---- LayerNorm over 64 rows (cross-lane over g groups) ----
    float s1a = 0.f, s1b = 0.f;
#pragma unroll
    for (int i = 0; i < 16; i++) { s1a += ga[i]; s1b += gb[i]; }
    s1a += __shfl_xor(s1a, 16, 64); s1a += __shfl_xor(s1a, 32, 64);
    s1b += __shfl_xor(s1b, 16, 64); s1b += __shfl_xor(s1b, 32, 64);
    const float mu0 = s1a * (1.f / 64.f), mu1 = s1b * (1.f / 64.f);
    float s2a = 0.f, s2b = 0.f;
#pragma unroll
    for (int i = 0; i < 16; i++) {
        const float d0 = ga[i] - mu0; s2a += d0 * d0;
        const float d1 = gb[i] - mu1; s2b += d1 * d1;
    }
    s2a += __shfl_xor(s2a, 16, 64); s2a += __shfl_xor(s2a, 32, 64);
    s2b += __shfl_xor(s2b, 16, 64); s2b += __shfl_xor(s2b, 32, 64);
    const float rs0 = rsqrtf(s2a * (1.f / 64.f) + 1e-5f);
    const float rs1 = rsqrtf(s2b * (1.f / 64.f) + 1e-5f);

    // ---- gn + hi/lo split + pack into B-frags ----
    BFrag Gh0[2], Gl0[2], Gh1[2], Gl1[2];
#pragma unroll
    for (int ks = 0; ks < 2; ks++) {
#pragma unroll
        for (int q = 0; q < 4; q++) {
            const int i0 = ks * 8 + 2 * q, i1 = i0 + 1;
            const int r0 = ((i0 >> 2) << 4) + 4 * g + (i0 & 3);
            const int r1 = ((i1 >> 2) << 4) + 4 * g + (i1 & 3);
            const float gnA0 = (ga[i0] - mu0) * rs0 * s_lng[r0] + s_lnb[r0];
            const float gnA1 = (ga[i1] - mu0) * rs0 * s_lng[r1] + s_lnb[r1];
            const float gnB0 = (gb[i0] - mu1) * rs1 * s_lng[r0] + s_lnb[r0];
            const float gnB1 = (gb[i1] - mu1) * rs1 * s_lng[r1] + s_lnb[r1];
            const unsigned short hA0 = f2bf_hw(gnA0), hA1 = f2bf_hw(gnA1);
            const unsigned short hB0 = f2bf_hw(gnB0), hB1 = f2bf_hw(gnB1);
            Gh0[ks].u[q] = pk2b(hA0, hA1);
            Gl0[ks].u[q] = cpack(gnA0 - bf2f(hA0), gnA1 - bf2f(hA1));
            Gh1[ks].u[q] = pk2b(hB0, hB1);
            Gl1[ks].u[q] = cpack(gnB0 - bf2f(hB0), gnB1 - bf2f(hB1));
        }
    }

    // ---- logits = gw2 @ gn via 3-term MFMA (two independent chains) ----
    f4v lacc0 = {0.f, 0.f, 0.f, 0.f}, lacc1 = {0.f, 0.f, 0.f, 0.f};
    {
        BFrag W0, W1, V0, V1;
        W0.q = sW2H[0 * 64 + lane]; W1.q = sW2H[1 * 64 + lane];
        V0.q = sW2L[0 * 64 + lane]; V1.q = sW2L[1 * 64 + lane];
        lacc0 = __builtin_amdgcn_mfma_f32_16x16x32_bf16(W0.s, Gh0[0].s, lacc0, 0, 0, 0);
        lacc1 = __builtin_amdgcn_mfma_f32_16x16x32_bf16(W0.s, Gh1[0].s, lacc1, 0, 0, 0);
        lacc0 = __builtin_amdgcn_mfma_f32_16x16x32_bf16(W1.s, Gh0[1].s, lacc0, 0, 0, 0);
        lacc1 = __builtin_amdgcn_mfma_f32_16x16x32_bf16(W1.s, Gh1[1].s, lacc1, 0, 0, 0);
        lacc0 = __builtin_amdgcn_mfma_f32_16x16x32_bf16(W0.s, Gl0[0].s, lacc0, 0, 0, 0);
        lacc1 = __builtin_amdgcn_mfma_f32_16x16x32_bf16(W0.s, Gl1[0].s, lacc1, 0, 0, 0);
        lacc0 = __builtin_amdgcn_mfma_f32_16x16x32_bf16(W1.s, Gl0[1].s, lacc0, 0, 0, 0);
        lacc1 = __builtin_amdgcn_mfma_f32_16x16x32_bf16(W1.s, Gl1[1].s, lacc1, 0, 0, 0);
        lacc0 = __builtin_amdgcn_mfma_f32_16x16x32_bf16(V0.s, Gh0[0].s, lacc0, 0, 0, 0);
        lacc1 = __builtin_amdgcn_mfma_f32_16x16x32_bf16(V0.s, Gh1[0].s, lacc1, 0, 0, 0);
        lacc0 = __builtin_amdgcn_mfma_f32_16x16x32_bf16(V1.s, Gh0[1].s, lacc0, 0, 0, 0);
        lacc1 = __builtin_amdgcn_mfma_f32_16x16x32_bf16(V1.s, Gh1[1].s, lacc1, 0, 0, 0);
    }

    float logit0[8], logit1[8];
#pragma unroll
    for (int j = 0; j < 4; j++) {
        const float o0 = __shfl_xor(lacc0[j], 16, 64);
        const float o1 = __shfl_xor(lacc1[j], 16, 64);
        logit0[j] = lacc0[j] + s_gb2[j];
        logit0[4 + j] = o0 + s_gb2[4 + j];
        logit1[j] = lacc1[j] + s_gb2[j];
        logit1[4 + j] = o1 + s_gb2[4 + j];
    }

    // ---- top-2 + margin flag (per point) ----
    unsigned mbits0 = 0, mbits1 = 0;
    bool flg0, flg1;
    {
        float m1 = logit0[0]; int i1 = 0;
#pragma unroll
        for (int e = 1; e < 8; e++) if (logit0[e] > m1) { m1 = logit0[e]; i1 = e; }
        float m2 = -INFINITY; int i2 = -1;
#pragma unroll
        for (int e = 0; e < 8; e++) if (e != i1 && logit0[e] > m2) { m2 = logit0[e]; i2 = e; }
        float m3 = -INFINITY;
#pragma unroll
        for (int e = 0; e < 8; e++) if (e != i1 && e != i2 && logit0[e] > m3) m3 = logit0[e];
#pragma unroll
        for (int e = 0; e < 8; e++) if (logit0[e] >= m2) mbits0 |= 1u << e;
        flg0 = (m2 - m3 < TAU);
    }
    {
        float m1 = logit1[0]; int i1 = 0;
#pragma unroll
        for (int e = 1; e < 8; e++) if (logit1[e] > m1) { m1 = logit1[e]; i1 = e; }
        float m2 = -INFINITY; int i2 = -1;
#pragma unroll
        for (int e = 0; e < 8; e++) if (e != i1 && logit1[e] > m2) { m2 = logit1[e]; i2 = e; }
        float m3 = -INFINITY;
#pragma unroll
        for (int e = 0; e < 8; e++) if (e != i1 && e != i2 && logit1[e] > m3) m3 = logit1[e];
#pragma unroll
        for (int e = 0; e < 8; e++) if (logit1[e] >= m2) mbits1 |= 1u << e;
        flg1 = (m2 - m3 < TAU);
    }

    const bool active = (g == 0);
    if (active) { sel[n0] = (unsigned char)mbits0; sel[n1] = (unsigned char)mbits1; }

#pragma unroll
    for (int e = 0; e < 8; e++) {
        const unsigned long long bal0 = __ballot(active && ((mbits0 >> e) & 1u));
        const unsigned long long bal1 = __ballot(active && ((mbits1 >> e) & 1u));
        if (lane == 0) atomicAdd(&s_cnt[e], (int)(__popcll(bal0) + __popcll(bal1)));
    }
    {
        const unsigned long long bal0 = __ballot(active && flg0);
        const unsigned long long bal1 = __ballot(active && flg1);
        const int p0 = (int)__popcll(bal0);
        int pos0 = 0;
        if (lane == 0 && (bal0 | bal1)) pos0 = atomicAdd(refcnt, p0 + (int)__popcll(bal1));
        pos0 = __shfl(pos0, 0, 64);
        if (active && flg0) {
            const int rank = (int)__popcll(bal0 & ((1ull << lane) - 1ull));
            reflist[pos0 + rank] = n0;
        }
        if (active && flg1) {
            const int rank = p0 + (int)__popcll(bal1 & ((1ull << lane) - 1ull));
            reflist[pos0 + rank] = n1;
        }
    }
    __syncthreads();
    if (t < 8) blkcnt[blockIdx.x * 8 + t] = s_cnt[t];
}

// ---------------- K1.25: exact-fp32 refine (reference op order), one wave per point ----------------
__global__ __launch_bounds__(256) void refine_kernel(
    const float* __restrict__ coords,
    const float* __restrict__ fw, const float* __restrict__ fb,
    const float* __restrict__ gw1, const float* __restrict__ gb1,
    const float* __restrict__ lng, const float* __restrict__ lnb,
    const float* __restrict__ gw2, const float* __restrict__ gb2,
    const int* __restrict__ reflist, const int* __restrict__ refcnt,
    unsigned char* __restrict__ sel, int* __restrict__ blkcnt)
{
    const int R = *refcnt;
    if (blockIdx.x * 4 >= R) return;            // uniform early exit, before any barrier

    __shared__ float s_gw1t[64 * 65];           // transposed + pad
    __shared__ float s_gw2[512];
    __shared__ float s_fw[192], s_fb[64], s_gb1[64], s_lng[64], s_lnb[64], s_gb2[8];
    __shared__ float s_f[4][64];

    const int t = threadIdx.x;
    for (int i = t; i < 4096; i += 256) s_gw1t[(i & 63) * 65 + (i >> 6)] = gw1[i];
    for (int i = t; i < 512; i += 256) s_gw2[i] = gw2[i];
    if (t < 192) s_fw[t] = fw[t];
    if (t < 64) { s_fb[t] = fb[t]; s_gb1[t] = gb1[t]; s_lng[t] = lng[t]; s_lnb[t] = lnb[t]; }
    if (t < 8) s_gb2[t] = gb2[t];
    __syncthreads();

    const int wv = t >> 6, lane = t & 63;
    for (int idx = blockIdx.x * 4 + wv; idx < R; idx += gridDim.x * 4) {
        const int n = reflist[idx];
        const float c0 = coords[n * 3], c1 = coords[n * 3 + 1], c2 = coords[n * 3 + 2];
        const float fr = s_fb[lane] + c0 * s_fw[lane * 3] + c1 * s_fw[lane * 3 + 1]
                       + c2 * s_fw[lane * 3 + 2];
        s_f[wv][lane] = fr;
        float a = s_gb1[lane];
#pragma unroll
        for (int k = 0; k < 64; k++)
            a += s_f[wv][k] * s_gw1t[k * 65 + lane];
        float mu = a;
#pragma unroll
        for (int d = 1; d < 64; d <<= 1) mu += __shfl_xor(mu, d, 64);
        mu *= (1.f / 64.f);
        const float dv = a - mu;
        float v = dv * dv;
#pragma unroll
        for (int d = 1; d < 64; d <<= 1) v += __shfl_xor(v, d, 64);
        const float rs = rsqrtf(v * (1.f / 64.f) + 1e-5f);
        const float gn = dv * rs * s_lng[lane] + s_lnb[lane];
        float lp[8];
#pragma unroll
        for (int e = 0; e < 8; e++) lp[e] = gn * s_gw2[e * 64 + lane];
#pragma unroll
        for (int e = 0; e < 8; e++) {
#pragma unroll
            for (int d = 1; d < 64; d <<= 1) lp[e] += __shfl_xor(lp[e], d, 64);
            lp[e] += s_gb2[e];
        }
        if (lane == 0) {
            float m1 = lp[0]; int i1 = 0;
#pragma unroll
            for (int e = 1; e < 8; e++) if (lp[e] > m1) { m1 = lp[e]; i1 = e; }
            float m2 = -INFINITY;
#pragma unroll
            for (int e = 0; e < 8; e++) if (e != i1 && lp[e] > m2) m2 = lp[e];
            unsigned mbits = 0;
#pragma unroll
            for (int e = 0; e < 8; e++) if (lp[e] >= m2) mbits |= 1u << e;
            const unsigned old = sel[n];
            if (mbits != old) {
                sel[n] = (unsigned char)mbits;
                const int b = n >> 7;
#pragma unroll
                for (int e = 0; e < 8; e++) {
                    const int was = (old >> e) & 1, now = (mbits >> e) & 1;
                    if (was != now) atomicAdd(&blkcnt[b * 8 + e], now - was);
                }
            }
        }
    }
}

// ---------------- K1.5: scan, one block per expert ----------------
__global__ __launch_bounds__(256) void scan_kernel(
    const int* __restrict__ blkcnt, int* __restrict__ baseoff,
    int* __restrict__ counts)
{
    const int e = blockIdx.x;          // 0..7
    const int t = threadIdx.x;         // each thread: 8 consecutive 128-pt groups
    const int lane = t & 63, wv = t >> 6;
    __shared__ int s_w[4];

    int v[8]; int sum = 0;
#pragma unroll
    for (int i = 0; i < 8; i++) { v[i] = blkcnt[(t * 8 + i) * 8 + e]; sum += v[i]; }
    int incl = sum;
#pragma unroll
    for (int d = 1; d < 64; d <<= 1) {
        const int x = __shfl_up(incl, d, 64);
        if (lane >= d) incl += x;
    }
    if (lane == 63) s_w[wv] = incl;
    __syncthreads();
    int woff = 0;
#pragma unroll
    for (int i = 0; i < 4; i++) if (i < wv) woff += s_w[i];
    int run = woff + incl - sum;
#pragma unroll
    for (int i = 0; i < 8; i++) { baseoff[(t * 8 + i) * 8 + e] = run; run += v[i]; }
    if (t == 255) counts[e] = run;
}

// ---------------- K2: scatter + aux ----------------
__global__ __launch_bounds__(128) void scatter_kernel(
    const unsigned char* __restrict__ sel, const int* __restrict__ baseoff,
    const int* __restrict__ counts, int* __restrict__ buckets, float* __restrict__ out)
{
    __shared__ int s_w0[8];
    const int t = threadIdx.x;
    const int n = blockIdx.x * 128 + t;
    if (blockIdx.x == 0 && t == 0) {
        double s = 0.0;
        for (int e = 0; e < 8; e++) { const double c = (double)counts[e]; s += c * c; }
        out[NPTS] = (float)(8.0 * s / ((double)NPTS * (double)NPTS));
    }
    const unsigned m = sel[n];
    const int w = t >> 6, lane = t & 63;
    unsigned long long bal[8];
#pragma unroll
    for (int e = 0; e < 8; e++) {
        bal[e] = __ballot((m >> e) & 1u);
        if (w == 0 && lane == 0) s_w0[e] = (int)__popcll(bal[e]);
    }
    __syncthreads();
#pragma unroll
    for (int e = 0; e < 8; e++) {
        if ((m >> e) & 1u) {
            int rank = (int)__popcll(bal[e] & ((1ull << lane) - 1ull));
            if (w == 1) rank += s_w0[e];
            buckets[e * NPTS + baseoff[blockIdx.x * 8 + e] + rank] = n;
        }
    }
}

// ---------------- K3: per-expert MFMA SIREN; 2 chains/wave; compact vchunk grid ----------------
__global__ __launch_bounds__(256) void expert_kernel(
    const float* __restrict__ coords,
    const float* __restrict__ M0, const float* __restrict__ b0p,
    const float* __restrict__ wl, const float* __restrict__ bl,
    const uint4* __restrict__ packA, const float* __restrict__ biasS,
    const int* __restrict__ counts, const int* __restrict__ buckets,
    float* __restrict__ out)
{
    __shared__ float s_b[192];
    __shared__ float s_wl[64];
    __shared__ float s_M0[192];
    __shared__ float s_b0p[64];
    __shared__ float s_bl;

    const int t = threadIdx.x;
    // prefix over ceil(counts[e]/128) — scalar, unrolled (no runtime-indexed reg arrays)
    const int c0n = (counts[0] + 127) >> 7;
    const int c1n = (counts[1] + 127) >> 7;
    const int c2n = (counts[2] + 127) >> 7;
    const int c3n = (counts[3] + 127) >> 7;
    const int c4n = (counts[4] + 127) >> 7;
    const int c5n = (counts[5] + 127) >> 7;
    const int c6n = (counts[6] + 127) >> 7;
    const int c7n = (counts[7] + 127) >> 7;
    const int p1 = c0n, p2 = p1 + c1n, p3 = p2 + c2n, p4 = p3 + c3n;
    const int p5 = p4 + c4n, p6 = p5 + c5n, p7 = p6 + c6n, total = p7 + c7n;

    bool first = true;
    for (int vc = blockIdx.x; vc < total; vc += gridDim.x) {
        int e = 0, pe = 0;
        if (vc >= p1) { e = 1; pe = p1; }
        if (vc >= p2) { e = 2; pe = p2; }
        if (vc >= p3) { e = 3; pe = p3; }
        if (vc >= p4) { e = 4; pe = p4; }
        if (vc >= p5) { e = 5; pe = p5; }
        if (vc >= p6) { e = 6; pe = p6; }
        if (vc >= p7) { e = 7; pe = p7; }
        const int cnt = counts[e];
        const int base = (vc - pe) * 128;

        if (!first) __syncthreads();
        first = false;
        if (t < 192) { s_b[t] = biasS[e * 192 + t]; s_M0[t] = M0[e * 192 + t]; }
        if (t < 64) { s_b0p[t] = b0p[e * 64 + t]; s_wl[t] = wl[e * 64 + t]; }
        if (t == 0) s_bl = bl[e];
        __syncthreads();

        const int lane = t & 63;
        const int wv = t >> 6;
        const int g = lane >> 4, c = lane & 15;
        const int i0 = base + wv * 32 + c;
        const int i1 = i0 + 16;
        const int id0 = (i0 < cnt) ? buckets[e * NPTS + i0] : -1;
        const int id1 = (i1 < cnt) ? buckets[e * NPTS + i1] : -1;

        const float a0 = (id0 >= 0) ? coords[id0 * 3] : 0.f;
        const float a1 = (id0 >= 0) ? coords[id0 * 3 + 1] : 0.f;
        const float a2 = (id0 >= 0) ? coords[id0 * 3 + 2] : 0.f;
        const float b0 = (id1 >= 0) ? coords[id1 * 3] : 0.f;
        const float b1 = (id1 >= 0) ? coords[id1 * 3 + 1] : 0.f;
        const float b2 = (id1 >= 0) ? coords[id1 * 3 + 2] : 0.f;

        // ---- layer 0 folded: z0[r] = b0p[r] + M0[r]·c in D layout ----
        f4v acc0[4], acc1[4];
#pragma unroll
        for (int tau = 0; tau < 4; tau++) {
#pragma unroll
            for (int j = 0; j < 4; j++) {
                const int r = tau * 16 + 4 * g + j;
                const float m0 = s_M0[r * 3], m1 = s_M0[r * 3 + 1], m2 = s_M0[r * 3 + 2];
                const float bb = s_b0p[r];
                acc0[tau][j] = bb + a0 * m0 + a1 * m1 + a2 * m2;
                acc1[tau][j] = bb + b0 * m0 + b1 * m1 + b2 * m2;
            }
        }

        // ---- sin + repack -> layer-1 B fragments ----
        BFrag B0[2], B1[2];
#pragma unroll
        for (int ks = 0; ks < 2; ks++) {
            B0[ks].u[0] = cpack(sinrev(acc0[2 * ks][0]), sinrev(acc0[2 * ks][1]));
            B0[ks].u[1] = cpack(sinrev(acc0[2 * ks][2]), sinrev(acc0[2 * ks][3]));
            B0[ks].u[2] = cpack(sinrev(acc0[2 * ks + 1][0]), sinrev(acc0[2 * ks + 1][1]));
            B0[ks].u[3] = cpack(sinrev(acc0[2 * ks + 1][2]), sinrev(acc0[2 * ks + 1][3]));
            B1[ks].u[0] = cpack(sinrev(acc1[2 * ks][0]), sinrev(acc1[2 * ks][1]));
            B1[ks].u[1] = cpack(sinrev(acc1[2 * ks][2]), sinrev(acc1[2 * ks][3]));
            B1[ks].u[2] = cpack(sinrev(acc1[2 * ks + 1][0]), sinrev(acc1[2 * ks + 1][1]));
            B1[ks].u[3] = cpack(sinrev(acc1[2 * ks + 1][2]), sinrev(acc1[2 * ks + 1][3]));
        }

        // ---- layer 1 (MFMA) ----
        {
#pragma unroll
            for (int tau = 0; tau < 4; tau++) {
                const float4 b = *(const float4*)&s_b[64 + tau * 16 + 4 * g];
                acc0[tau][0] = b.x; acc0[tau][1] = b.y; acc0[tau][2] = b.z; acc0[tau][3] = b.w;
                acc1[tau][0] = b.x; acc1[tau][1] = b.y; acc1[tau][2] = b.z; acc1[tau][3] = b.w;
            }
            const uint4* Ab = packA + (size_t)((e * 3 + 1) * 8) * 64 + lane;
#pragma unroll
            for (int tau = 0; tau < 4; tau++) {
                BFrag A0, A1;
                A0.q = Ab[(tau * 2 + 0) * 64];
                A1.q = Ab[(tau * 2 + 1) * 64];
                acc0[tau] = __builtin_amdgcn_mfma_f32_16x16x32_bf16(A0.s, B0[0].s, acc0[tau], 0, 0, 0);
                acc0[tau] = __builtin_amdgcn_mfma_f32_16x16x32_bf16(A1.s, B0[1].s, acc0[tau], 0, 0, 0);
                acc1[tau] = __builtin_amdgcn_mfma_f32_16x16x32_bf16(A0.s, B1[0].s, acc1[tau], 0, 0, 0);
                acc1[tau] = __builtin_amdgcn_mfma_f32_16x16x32_bf16(A1.s, B1[1].s, acc1[tau], 0, 0, 0);
            }
#pragma unroll
            for (int ks = 0; ks < 2; ks++) {
                B0[ks].u[0] = cpack(sinrev(acc0[2 * ks][0]), sinrev(acc0[2 * ks][1]));
                B0[ks].u[1] = cpack(sinrev(acc0[2 * ks][2]), sinrev(acc0[2 * ks][3]));
                B0[ks].u[2] = cpack(sinrev(acc0[2 * ks + 1][0]), sinrev(acc0[2 * ks + 1][1]));
                B0[ks].u[3] = cpack(sinrev(acc0[2 * ks + 1][2]), sinrev(acc0[2 * ks + 1][3]));
                B1[ks].u[0] = cpack(sinrev(acc1[2 * ks][0]), sinrev(acc1[2 * ks][1]));
                B1[ks].u[1] = cpack(sinrev(acc1[2 * ks][2]), sinrev(acc1[2 * ks][3]));
                B1[ks].u[2] = cpack(sinrev(acc1[2 * ks + 1][0]), sinrev(acc1[2 * ks + 1][1]));
                B1[ks].u[3] = cpack(sinrev(acc1[2 * ks + 1][2]), sinrev(acc1[2 * ks + 1][3]));
            }
        }

        // ---- layer 2 + final dot ----
        {
#pragma unroll
            for (int tau = 0; tau < 4; tau++) {
                const float4 b = *(const float4*)&s_b[128 + tau * 16 + 4 * g];
                acc0[tau][0] = b.x; acc0[tau][1] = b.y; acc0[tau][2] = b.z; acc0[tau][3] = b.w;
                acc1[tau][0] = b.x; acc1[tau][1] = b.y; acc1[tau][2] = b.z; acc1[tau][3] = b.w;
            }
            const uint4* Ab = packA + (size_t)((e * 3 + 2) * 8) * 64 + lane;
#pragma unroll
            for (int tau = 0; tau < 4; tau++) {
                BFrag A0, A1;
                A0.q = Ab[(tau * 2 + 0) * 64];
                A1.q = Ab[(tau * 2 + 1) * 64];
                acc0[tau] = __builtin_amdgcn_mfma_f32_16x16x32_bf16(A0.s, B0[0].s, acc0[tau], 0, 0, 0);
                acc0[tau] = __builtin_amdgcn_mfma_f32_16x16x32_bf16(A1.s, B0[1].s, acc0[tau], 0, 0, 0);
                acc1[tau] = __builtin_amdgcn_mfma_f32_16x16x32_bf16(A0.s, B1[0].s, acc1[tau], 0, 0, 0);
                acc1[tau] = __builtin_amdgcn_mfma_f32_16x16x32_bf16(A1.s, B1[1].s, acc1[tau], 0, 0, 0);
            }
            float px0 = 0.f, px1 = 0.f;
#pragma unroll
            for (int tau = 0; tau < 4; tau++) {
                const float4 w = *(const float4*)&s_wl[tau * 16 + 4 * g];
                px0 += sinrev(acc0[tau][0]) * w.x + sinrev(acc0[tau][1]) * w.y
                     + sinrev(acc0[tau][2]) * w.z + sinrev(acc0[tau][3]) * w.w;
                px1 += sinrev(acc1[tau][0]) * w.x + sinrev(acc1[tau][1]) * w.y
                     + sinrev(acc1[tau][2]) * w.z + sinrev(acc1[tau][3]) * w.w;
            }
            px0 += __shfl_xor(px0, 16, 64); px0 += __shfl_xor(px0, 32, 64);
            px1 += __shfl_xor(px1, 16, 64); px1 += __shfl_xor(px1, 32, 64);
            if (g == 0) {
                if (id0 >= 0) atomicAdd(&out[id0], px0 + s_bl);
                if (id1 >= 0) atomicAdd(&out[id1], px1 + s_bl);
            }
        }
    }
}

extern "C" void kernel_launch(void* const* d_in, const int* in_sizes, int n_in,
                              void* d_out, int out_size, void* d_ws, size_t ws_size,
                              hipStream_t stream)
{
    const float* coords = (const float*)d_in[0];
    const float* fw  = (const float*)d_in[1];
    const float* fb  = (const float*)d_in[2];
    const float* gw1 = (const float*)d_in[3];
    const float* gb1 = (const float*)d_in[4];
    const float* lng = (const float*)d_in[5];
    const float* lnb = (const float*)d_in[6];
    const float* gw2 = (const float*)d_in[7];
    const float* gb2 = (const float*)d_in[8];
    const float* we0 = (const float*)d_in[9];
    const float* be0 = (const float*)d_in[10];
    const float* wm  = (const float*)d_in[11];
    const float* bm  = (const float*)d_in[12];
    const float* wl  = (const float*)d_in[13];
    const float* bl  = (const float*)d_in[14];
    float* out = (float*)d_out;

    char* ws = (char*)d_ws;
    int* counts           = (int*)ws;                        // 64
    int* buckets          = (int*)(ws + 64);                 // 8*NPTS*4 = 8388608
    uint4* packA          = (uint4*)(ws + 8388672);          // 196608
    float* biasS          = (float*)(ws + 8585280);          // 6144
    int* blkcnt           = (int*)(ws + 8591424);            // 65536
    int* baseoff          = (int*)(ws + 8656960);            // 65536
    unsigned char* sel    = (unsigned char*)(ws + 8722496);  // 262144
    uint4* packGW2H       = (uint4*)(ws + 8984640);          // 2048
    uint4* packGW2L       = (uint4*)(ws + 8986688);          // 2048
    int* reflist          = (int*)(ws + 8988736);            // 1048576
    int* refcnt           = (int*)(ws + 10037312);           // 64
    float* M1             = (float*)(ws + 10037376);         // 768
    float* b1p            = (float*)(ws + 10038144);         // 256
    float* M0             = (float*)(ws + 10038400);         // 6144
    float* b0p            = (float*)(ws + 10044544);         // 2048

    prep_kernel<<<64, 256, 0, stream>>>(we0, be0, wm, bm, gw1, gw2, fw, fb, gb1,
                                        packA, biasS, packGW2H, packGW2L, M1, b1p,
                                        M0, b0p, refcnt);
    gate_kernel<<<GBLK, 256, 0, stream>>>(coords, M1, b1p, lng, lnb, gb2,
                                          packGW2H, packGW2L,
                                          sel, blkcnt, reflist, refcnt, out);
    refine_kernel<<<256, 256, 0, stream>>>(coords, fw, fb, gw1, gb1, lng, lnb, gw2, gb2,
                                           reflist, refcnt, sel, blkcnt);
    scan_kernel<<<8, 256, 0, stream>>>(blkcnt, baseoff, counts);
    scatter_kernel<<<GBLK, 128, 0, stream>>>(sel, baseoff, counts, buckets, out);
    expert_kernel<<<2056, 256, 0, stream>>>(coords, M0, b0p, wl, bl, packA, biasS,
                                            counts, buckets, out);
}